// Round 7
// baseline (245.419 us; speedup 1.0000x reference)
//
#include <hip/hip_runtime.h>
#include <hip/hip_bf16.h>
#include <stdint.h>

// Problem: B=4, N=1024, C=768, H=12, hd=64.
// out_x = (attn(qx,kx,vx,+) + attn(qyo,kx,vx,-)) @ Wp^T + bp
// out_y = (attn(qy,ky,vx,+) + attn(qxo,ky,vx,-)) @ Wp^T + bp   (vy = vx!)
// qkv[b,n, j*768 + h*64 + d], j in {0:qo, 1:q, 2:k, 3:v}
// NOTE: w_qkv rows j=0 are pre-scaled by -0.125*log2(e), j=1 by +0.125*log2(e)
// in cvt_bf16, so attention scores emerge in the log2 domain with sign folded:
// softmax is exp2(s) directly for BOTH self and cross attends.

#define BB 4
#define NN 1024
#define CC 768
#define HH 12
#define HD 64

typedef unsigned short u16;
typedef short short8 __attribute__((ext_vector_type(8)));
typedef float f32x4 __attribute__((ext_vector_type(4)));

extern "C" __device__ float __ocml_native_exp2_f32(float);

__device__ __forceinline__ u16 f2bf(float f) {
  unsigned int u = __float_as_uint(f);
  return (u16)((u + 0x7fffu + ((u >> 16) & 1u)) >> 16);
}

__device__ __forceinline__ void load_lds16(const u16* g, u16* l) {
  __builtin_amdgcn_global_load_lds((__attribute__((address_space(1))) const void*)g,
                                   (__attribute__((address_space(3))) void*)l, 16, 0, 0);
}

// fp32 -> bf16 conversion: seg 0=x, 1=y, 2=w_qkv (query rows pre-scaled), 3=w_proj
__global__ __launch_bounds__(256)
void cvt_bf16(const float* __restrict__ x, const float* __restrict__ y,
              const float* __restrict__ wq, const float* __restrict__ wp,
              u16* __restrict__ xb, u16* __restrict__ yb,
              u16* __restrict__ wqb, u16* __restrict__ wpb)
{
  const int seg = blockIdx.y;
  const float* src = seg == 0 ? x : (seg == 1 ? y : (seg == 2 ? wq : wp));
  u16* dst = seg == 0 ? xb : (seg == 1 ? yb : (seg == 2 ? wqb : wpb));
  const int n = (seg == 3) ? 768 * 768 : ((seg == 2) ? 3072 * 768 : 4096 * 768);
  const int i = (blockIdx.x * 256 + threadIdx.x) * 8;
  if (i >= n) return;
  float sc = 1.0f;
  if (seg == 2) {
    const int row = i / 768;  // output feature p; j = p/768
    sc = (row < 768) ? -0.18033688f : (row < 1536 ? 0.18033688f : 1.0f);
  }
  float4 a = *(const float4*)(src + i);
  float4 b = *(const float4*)(src + i + 4);
  ushort4 u0 = {f2bf(a.x * sc), f2bf(a.y * sc), f2bf(a.z * sc), f2bf(a.w * sc)};
  ushort4 u1 = {f2bf(b.x * sc), f2bf(b.y * sc), f2bf(b.z * sc), f2bf(b.w * sc)};
  *(ushort4*)(dst + i) = u0;
  *(ushort4*)(dst + i + 4) = u1;
}

// V^T prepass: VT[(bh*64 + d)*1024 + key] = qkv_x[b, key, 3*768 + h*64 + d]
// 1-D grid, XCD-swizzled so producer blocks land on the XCD that consumes VT[bh].
__global__ __launch_bounds__(256)
void vtrans(const u16* __restrict__ qkvx, u16* __restrict__ VT)
{
  const int blk = blockIdx.x;                 // 1536 blocks
  const int xcd = blk & 7, slot = blk >> 3;   // 192 slots
  const int bh = (slot >> 5) * 8 + xcd;       // 6 groups x 8 = 48
  const int kt = slot & 31;                   // 32 key-tiles
  const int b = bh / HH, h = bh % HH;
  const int t = threadIdx.x;
  const int key = kt * 32 + (t >> 3), d0 = (t & 7) * 8;
  uint4 v = *(const uint4*)(qkvx + (size_t)(b * NN + key) * 3072 + 3 * CC + h * HD + d0);
  u16 e[8];
  *(uint4*)e = v;
#pragma unroll
  for (int i = 0; i < 8; i++)
    VT[(size_t)(bh * 64 + d0 + i) * 1024 + key] = e[i];
}

// MFMA GEMM: C[m,p] = A[m,:] . W[p,:] (+bias). 128x128 tile, 4 waves, BK=64.
// global_load_lds width=16 staging + XOR swizzle (chunk ^ row&7).
template<int NP, bool BF16OUT, bool BIAS>
__global__ __launch_bounds__(256)
void gemm_mfma(const u16* __restrict__ A0, const u16* __restrict__ A1,
               const u16* __restrict__ W, const float* __restrict__ bias,
               void* __restrict__ C0, void* __restrict__ C1)
{
  __shared__ u16 As[128 * 64];
  __shared__ u16 Bs[128 * 64];
  const u16* A = blockIdx.z ? A1 : A0;
  void* C = blockIdx.z ? C1 : C0;
  const int m0 = blockIdx.y * 128, n0 = blockIdx.x * 128;
  const int t = threadIdx.x, w = t >> 6, lane = t & 63;
  const int c = lane & 15, qq = lane >> 4;
  const int mq = (w >> 1) * 64, nq = (w & 1) * 64;

  const int lrow = lane >> 3;
  const int lchunk = (lane & 7) ^ lrow;
  size_t arow[4], brow[4];
#pragma unroll
  for (int i = 0; i < 4; i++) {
    const int r = (w * 4 + i) * 8 + lrow;
    arow[i] = (size_t)(m0 + r) * 768 + lchunk * 8;
    brow[i] = (size_t)(n0 + r) * 768 + lchunk * 8;
  }

  f32x4 acc[4][4] = {};
  for (int k0 = 0; k0 < 768; k0 += 64) {
    __syncthreads();
#pragma unroll
    for (int i = 0; i < 4; i++) {
      load_lds16(A + arow[i] + k0, As + (w * 4 + i) * 512);
      load_lds16(W + brow[i] + k0, Bs + (w * 4 + i) * 512);
    }
    __syncthreads();
#pragma unroll
    for (int s = 0; s < 2; s++) {
      const int swz = ((s * 4 + qq) ^ (c & 7)) * 8;
      short8 af[4], bf[4];
#pragma unroll
      for (int i = 0; i < 4; i++)
        af[i] = *(const short8*)&As[(mq + i * 16 + c) * 64 + swz];
#pragma unroll
      for (int j = 0; j < 4; j++)
        bf[j] = *(const short8*)&Bs[(nq + j * 16 + c) * 64 + swz];
#pragma unroll
      for (int i = 0; i < 4; i++)
#pragma unroll
        for (int j = 0; j < 4; j++)
          acc[i][j] = __builtin_amdgcn_mfma_f32_16x16x32_bf16(af[i], bf[j], acc[i][j], 0, 0, 0);
    }
  }
  float bj[4] = {0.f, 0.f, 0.f, 0.f};
  if (BIAS) {
#pragma unroll
    for (int j = 0; j < 4; j++) bj[j] = bias[n0 + nq + c + j * 16];
  }
#pragma unroll
  for (int i = 0; i < 4; i++)
#pragma unroll
    for (int r = 0; r < 4; r++) {
      const size_t row = (size_t)(m0 + mq + i * 16 + qq * 4 + r) * NP + n0 + nq + c;
      if (BF16OUT) {
#pragma unroll
        for (int j = 0; j < 4; j++)
          ((u16*)C)[row + j * 16] = f2bf(acc[i][j][r]);
      } else {
#pragma unroll
        for (int j = 0; j < 4; j++)
          ((float*)C)[row + j * 16] = acc[i][j][r] + bj[j];
      }
    }
}

// MFMA attention v4. 1-D grid (768 = 3 blocks/CU), XCD-swizzled: the 16
// blocks sharing one (b,head) land on one XCD so K/VT (384 KB/bh) stay in
// its 4 MB L2. One workgroup: (b,head), 128 q-rows, pair in {x,y}; each wave
// owns 16 q-rows x 2 row-groups x {self, cross}. K/VT double-buffered via
// global_load_lds w=16: ONE barrier per chunk, next chunk's loads issued
// right after the barrier so the vmcnt(0) drain at the following barrier
// waits on ~fully-landed loads. Scores in log2 domain -> exp2 direct; row
// denominators via ones-MFMA; P bf16-truncated (common-mode cancels).
__global__ __launch_bounds__(256, 3)
void attn_pair_mfma(const u16* __restrict__ qkvx, const u16* __restrict__ qkvy,
                    const u16* __restrict__ VT,
                    u16* __restrict__ sum_x, u16* __restrict__ sum_y)
{
  __shared__ __align__(16) u16 smem[24576];  // 48KB: K 2x8K | VT 2x8K | P 4K/wave
  float (*Of)[68] = (float(*)[68])smem;      // epilogue alias (34816 B)

  // XCD-aware decode (perf heuristic only)
  const int blk = blockIdx.x;                // 768 blocks
  const int xcd = blk & 7, slot = blk >> 3;  // 96 slots
  const int bh = (slot >> 4) * 8 + xcd;      // 6 groups x 8 = 48
  const int qt = (slot & 15) >> 1, pair = slot & 1;
  const int b = bh / HH, head = bh % HH;
  const u16* q1 = pair ? qkvy : qkvx;  // self q   (j=1, +scale folded)
  const u16* q2 = pair ? qkvx : qkvy;  // cross qo (j=0, -scale folded)
  const u16* ks = pair ? qkvy : qkvx;  // k (j=2)
  u16* outp = pair ? sum_y : sum_x;

  const int t = threadIdx.x, w = t >> 6, lane = t & 63;
  const int c = lane & 15, qq = lane >> 4;

  // Q A-frags: 4 sets = (g0,self),(g0,cross),(g1,self),(g1,cross)
  short8 Qf[4][2];
#pragma unroll
  for (int g = 0; g < 2; g++) {
    const int qrow = qt * 128 + g * 64 + w * 16 + c;
    const u16* qs = q1 + (size_t)(b * NN + qrow) * 3072 + CC + head * HD + qq * 8;
    const u16* qc = q2 + (size_t)(b * NN + qrow) * 3072 + head * HD + qq * 8;
    Qf[g * 2][0] = *(const short8*)qs;
    Qf[g * 2][1] = *(const short8*)(qs + 32);
    Qf[g * 2 + 1][0] = *(const short8*)qc;
    Qf[g * 2 + 1][1] = *(const short8*)(qc + 32);
  }

  const u16* kbase = ks + (size_t)(b * NN) * 3072 + 2 * CC + head * HD;
  const u16* vtb = VT + (size_t)(bh * 64) * 1024;

  const int lr = lane >> 3;
  const int sc8 = ((lane & 7) ^ lr) * 8;

  u16* Pw = smem + 16384 + w * 2048;  // 2 wave-private 16x64 tiles (self, cross)

  short8 ones;
#pragma unroll
  for (int i = 0; i < 8; i++) ones[i] = (short)0x3F80;  // bf16 1.0

  f32x4 O[4][4] = {};  // [set][t4]
  f32x4 L[4] = {};

  const int cx = c & 7;
  const int off0 = (qq ^ cx) * 8;
  const int off1 = ((4 + qq) ^ cx) * 8;

  // double-buffered staging: 4 issues/wave into half `hf`
  auto stage = [&](int c16, int hf) {
    const int bo = hf * 4096;
#pragma unroll
    for (int i = 0; i < 2; i++) {
      const int r = (2 * w + i) * 8 + lr;
      load_lds16(kbase + (size_t)(c16 * 64 + r) * 3072 + sc8,
                 smem + bo + (2 * w + i) * 512);
      load_lds16(vtb + (size_t)r * 1024 + c16 * 64 + sc8,
                 smem + 8192 + bo + (2 * w + i) * 512);
    }
  };

  stage(0, 0);
  for (int c16 = 0; c16 < 16; ++c16) {
    __syncthreads();  // chunk c16 staged (loads have been in flight all of
                      // prev compute); also: all reads of this half done
    if (c16 < 15) stage(c16 + 1, (c16 + 1) & 1);
    const u16* Kc = smem + (c16 & 1) * 4096;
    const u16* Vc = smem + 8192 + (c16 & 1) * 4096;

#pragma unroll
    for (int g = 0; g < 2; g++) {
      // S = Q K^T for self + cross of this row-group
      f32x4 ss[4], sx[4];
#pragma unroll
      for (int t4 = 0; t4 < 4; t4++) {
        const u16* kr = Kc + (16 * t4 + c) * 64;
        short8 k0 = *(const short8*)(kr + off0);
        short8 k1 = *(const short8*)(kr + off1);
        f32x4 z = {0.f, 0.f, 0.f, 0.f};
        z = __builtin_amdgcn_mfma_f32_16x16x32_bf16(Qf[g * 2][0], k0, z, 0, 0, 0);
        ss[t4] = __builtin_amdgcn_mfma_f32_16x16x32_bf16(Qf[g * 2][1], k1, z, 0, 0, 0);
        f32x4 z2 = {0.f, 0.f, 0.f, 0.f};
        z2 = __builtin_amdgcn_mfma_f32_16x16x32_bf16(Qf[g * 2 + 1][0], k0, z2, 0, 0, 0);
        sx[t4] = __builtin_amdgcn_mfma_f32_16x16x32_bf16(Qf[g * 2 + 1][1], k1, z2, 0, 0, 0);
      }
      // exp2 + truncated-bf16 P (wave-private buffers; DS ops in-order per
      // wave make the g0-read -> g1-write reuse safe without barriers)
      u16* Ps = Pw;
      u16* Pc2 = Pw + 1024;
#pragma unroll
      for (int t4 = 0; t4 < 4; t4++)
#pragma unroll
        for (int r = 0; r < 4; r++) {
          const int row = 4 * qq + r;
          const int poff = row * 64 + ((2 * t4 + (c >> 3)) ^ (row & 7)) * 8 + cx;
          float es = __ocml_native_exp2_f32(ss[t4][r]);
          float ec = __ocml_native_exp2_f32(sx[t4][r]);
          Ps[poff] = (u16)(__float_as_uint(es) >> 16);
          Pc2[poff] = (u16)(__float_as_uint(ec) >> 16);
        }
      // P A-frags + L (ones-MFMA) + PV
      short8 Pf[2][2];
      const u16* prs = Ps + c * 64;
      const u16* prc = Pc2 + c * 64;
      Pf[0][0] = *(const short8*)(prs + off0);
      Pf[0][1] = *(const short8*)(prs + off1);
      Pf[1][0] = *(const short8*)(prc + off0);
      Pf[1][1] = *(const short8*)(prc + off1);
      L[g * 2] = __builtin_amdgcn_mfma_f32_16x16x32_bf16(Pf[0][0], ones, L[g * 2], 0, 0, 0);
      L[g * 2] = __builtin_amdgcn_mfma_f32_16x16x32_bf16(Pf[0][1], ones, L[g * 2], 0, 0, 0);
      L[g * 2 + 1] = __builtin_amdgcn_mfma_f32_16x16x32_bf16(Pf[1][0], ones, L[g * 2 + 1], 0, 0, 0);
      L[g * 2 + 1] = __builtin_amdgcn_mfma_f32_16x16x32_bf16(Pf[1][1], ones, L[g * 2 + 1], 0, 0, 0);
#pragma unroll
      for (int t4 = 0; t4 < 4; t4++) {
        const u16* vr = Vc + (16 * t4 + c) * 64;
        short8 v0 = *(const short8*)(vr + off0);
        short8 v1 = *(const short8*)(vr + off1);
        O[g * 2][t4] = __builtin_amdgcn_mfma_f32_16x16x32_bf16(Pf[0][0], v0, O[g * 2][t4], 0, 0, 0);
        O[g * 2][t4] = __builtin_amdgcn_mfma_f32_16x16x32_bf16(Pf[0][1], v1, O[g * 2][t4], 0, 0, 0);
        O[g * 2 + 1][t4] = __builtin_amdgcn_mfma_f32_16x16x32_bf16(Pf[1][0], v0, O[g * 2 + 1][t4], 0, 0, 0);
        O[g * 2 + 1][t4] = __builtin_amdgcn_mfma_f32_16x16x32_bf16(Pf[1][1], v1, O[g * 2 + 1][t4], 0, 0, 0);
      }
    }
  }

  __syncthreads();  // all waves done with K/VT/P -> realias as Of
#pragma unroll
  for (int g = 0; g < 2; g++) {
    float is[4], ic[4];
#pragma unroll
    for (int r = 0; r < 4; r++) {
      is[r] = 1.0f / L[g * 2][r];
      ic[r] = 1.0f / L[g * 2 + 1][r];
    }
#pragma unroll
    for (int t4 = 0; t4 < 4; t4++)
#pragma unroll
      for (int r = 0; r < 4; r++)
        Of[g * 64 + w * 16 + 4 * qq + r][16 * t4 + c] =
            O[g * 2][t4][r] * is[r] + O[g * 2 + 1][t4][r] * ic[r];
  }
  __syncthreads();
  // out[b, qt*128+row, head*64+d] (bf16, coalesced)
#pragma unroll
  for (int p = 0; p < 8; p++) {
    const int idx = p * 256 + t;
    const int row = idx >> 4, c4 = (idx & 15) * 4;
    float4 v = *(const float4*)&Of[row][c4];
    ushort4 u = {f2bf(v.x), f2bf(v.y), f2bf(v.z), f2bf(v.w)};
    *(ushort4*)(outp + (size_t)(b * NN + qt * 128 + row) * CC + head * HD + c4) = u;
  }
}

extern "C" void kernel_launch(void* const* d_in, const int* in_sizes, int n_in,
                              void* d_out, int out_size, void* d_ws, size_t ws_size,
                              hipStream_t stream)
{
  const float* x      = (const float*)d_in[0];
  const float* y      = (const float*)d_in[1];
  const float* w_qkv  = (const float*)d_in[2];
  const float* w_proj = (const float*)d_in[3];
  const float* b_proj = (const float*)d_in[4];

  // ws layout (75.1 MB used):
  //   qkv_x 25.2 | qkv_y 25.2 | sum_x 6.3 (alias x_bf) | sum_y 6.3 (alias y_bf)
  //   | wq_bf 4.7 | wp_bf 1.2 | VT 6.3
  u16* qkv_x = (u16*)d_ws;
  u16* qkv_y = qkv_x + (size_t)4096 * 3072;
  u16* rest = qkv_y + (size_t)4096 * 3072;
  u16* sum_x = rest;
  u16* sum_y = sum_x + (size_t)4096 * 768;
  u16* x_bf  = rest;                       // aliases sum_x (dead after QKV)
  u16* y_bf  = x_bf + (size_t)4096 * 768;  // aliases sum_y
  u16* wq_bf = y_bf + (size_t)4096 * 768;
  u16* wp_bf = wq_bf + (size_t)3072 * 768;
  u16* VT    = wp_bf + (size_t)768 * 768;
  float* out_x = (float*)d_out;
  float* out_y = out_x + (size_t)4096 * 768;

  // 0) fp32 -> bf16 (w_qkv query rows pre-scaled by ±0.125·log2e)
  cvt_bf16<<<dim3(1536, 4), 256, 0, stream>>>(x, y, w_qkv, w_proj,
                                              x_bf, y_bf, wq_bf, wp_bf);

  // 1) QKV via MFMA: qkv_{x,y} = {x,y}_bf @ wq_bf^T (bf16 out)
  gemm_mfma<3072, true, false><<<dim3(24, 32, 2), 256, 0, stream>>>(
      x_bf, y_bf, wq_bf, nullptr, qkv_x, qkv_y);

  // 1.5) V^T prepass (v always from x), XCD-swizzled
  vtrans<<<dim3(1536), 256, 0, stream>>>(qkv_x, VT);

  // 2) paired MFMA attention -> sum_x, sum_y (bf16), XCD-swizzled 1-D grid
  attn_pair_mfma<<<dim3(768), 256, 0, stream>>>(qkv_x, qkv_y, VT, sum_x, sum_y);

  // 3) out = sum @ wp_bf^T + b_proj (f32, MFMA)
  gemm_mfma<768, false, true><<<dim3(6, 32, 2), 256, 0, stream>>>(
      sum_x, sum_y, wp_bf, b_proj, out_x, out_y);
}